// Round 18
// baseline (90.109 us; speedup 1.0000x reference)
//
#include <hip/hip_runtime.h>

// SpectralConv2dRealFreq: B=16, Cin=Cout=64, H=W=128, modes=33 (k in [-16,16])
// out = Re( iDFT2_trunc( (DFT2_trunc(x)) * (wr + i*wi) ) ), separable 1/sqrt(N) DFTs.
//
// Round 18: zero scattered loads. R17 proved the 0.85 TB/s wall is the
// dependent-scattered-4B-load pattern itself (X loads alone reproduce it,
// even L2-resident). Mix inner loop now touches ONLY LDS:
//   wpack:   linear float4 weight read -> Wpk[opair][mg][c][oo][m_l] bf16-pairs
//   xrepack: X2u -> Xp[m][c][b] (zero-padded to 1104 modes)
//   vmix:    block=(opair,mg16): stage 64KB X slab + 8KB W slab (contiguous
//            uint4), c-loop = pure LDS+FMA; outputs via LDS tile, uint2 stores.
//   (tables / fwd / inv unchanged; bf16 weights = R5-R17 numerics)

#define NB   16
#define NC   64
#define NO   64
#define NH   128
#define NW   128
#define NM   33
#define WMODE (NM*NM)    // 1089 linear modes
#define MPAD  1092       // Kbf mode stride
#define XPM   1104       // Xp padded modes (69*16)
#define MG    69         // 16-mode groups
#define NIMG 1024
#define NTOT (64*64*WMODE)   // dwords per weight plane

typedef __attribute__((ext_vector_type(8))) short s8v;   // 8 bf16 (4 VGPRs)
typedef __attribute__((ext_vector_type(4))) float f4v;   // MFMA accumulator

__device__ inline unsigned short f2bf(float f) {
  union { float f; unsigned u; } v; v.f = f;
  unsigned r = (v.u + 0x7FFFu + ((v.u >> 16) & 1u)) >> 16;   // RNE
  return (unsigned short)r;
}

__device__ inline float bflo(unsigned u) {
  union { unsigned u; float f; } cv; cv.u = u << 16; return cv.f;
}
__device__ inline float bfhi(unsigned u) {
  union { unsigned u; float f; } cv; cv.u = u & 0xFFFF0000u; return cv.f;
}

__device__ inline s8v pack8(float4 a, float4 b) {
  s8v r;
  r[0] = (short)f2bf(a.x); r[1] = (short)f2bf(a.y);
  r[2] = (short)f2bf(a.z); r[3] = (short)f2bf(a.w);
  r[4] = (short)f2bf(b.x); r[5] = (short)f2bf(b.y);
  r[6] = (short)f2bf(b.z); r[7] = (short)f2bf(b.w);
  return r;
}

__device__ inline uint2 pack4(f4v a) {
  uint2 p;
  p.x = (unsigned)f2bf(a[0]) | ((unsigned)f2bf(a[1]) << 16);
  p.y = (unsigned)f2bf(a[2]) | ((unsigned)f2bf(a[3]) << 16);
  return p;
}

// stacked-phase value: f in [0,33): cos row f; [33,66): sin row f-33; >=66: 0
__device__ inline unsigned short phase_bf(int f, int x) {
  if (f >= 66) return 0;
  int g = (f < 33) ? f : f - 33;
  int fr = (g <= 16) ? g : g + 95;          // signed freq mod 128
  int ph = (fr * x) & 127;                  // exact integer phase
  float ang = (float)ph * 0.04908738521234052f;   // 2*pi/128
  float v = ((f < 33) ? cosf(ang) : sinf(ang)) * 0.08838834764831845f;  // /sqrt(128)
  return f2bf(v);
}

// --------------------------------------------------- fragment-layout tables
__global__ __launch_bounds__(256) void spc_tables(short* __restrict__ T1,
                                                  short* __restrict__ T2,
                                                  short* __restrict__ T3,
                                                  short* __restrict__ T4) {
  int tid = blockIdx.x * 256 + threadIdx.x;
  if (tid >= 49152) return;
  int f, x; short* dst;
  if (tid < 10240) {
    int e = tid & 7, l = (tid >> 3) & 63, q = tid >> 9;     // q = ks*5+jt
    int ks = q / 5, jt = q - 5 * ks;
    f = jt * 16 + (l & 15); x = ks * 32 + (l >> 4) * 8 + e; dst = T1 + tid;
  } else if (tid < 20480) {
    int u = tid - 10240;
    int e = u & 7, l = (u >> 3) & 63, q = u >> 9;           // q = it*4+ks
    int it = q >> 2, ks = q & 3;
    f = it * 16 + (l & 15); x = ks * 32 + (l >> 4) * 8 + e; dst = T2 + u;
  } else if (tid < 36864) {
    int u = tid - 20480;
    int e = u & 7, l = (u >> 3) & 63, q = u >> 9;           // q = (cs*2+ks)*8+mt
    int cs = q >> 4, ks = (q >> 3) & 1, mt = q & 7;
    int j = ks * 32 + (l >> 4) * 8 + e;
    f = (j < 33) ? cs * 33 + j : 66;
    x = mt * 16 + (l & 15); dst = T3 + u;
  } else {
    int u = tid - 36864;
    int e = u & 7, l = (u >> 3) & 63, q = u >> 9;           // q = nt*3+ks
    int nt = q / 3, ks = q - 3 * nt;
    int i2 = ks * 32 + (l >> 4) * 8 + e;
    if (i2 < 48) f = (i2 < 33) ? i2 : 66;
    else         f = (i2 - 48 < 33) ? 33 + (i2 - 48) : 66;
    x = nt * 16 + (l & 15); dst = T4 + u;
  }
  *dst = (short)phase_bf(f, x);
}

// ------------------------------------------------------------ weight pack
// Linear float4 read of both planes; write packed bf16 pairs:
// Wpk[((((o>>1)*MG + (m>>4))*64 + c)*2 + (o&1))*16 + (m&15)] = bf16(wr)|bf16(wi)<<16
__global__ __launch_bounds__(256) void spc_wpack(const float* __restrict__ wr,
                                                 const float* __restrict__ wi,
                                                 unsigned* __restrict__ Wpk) {
  const int t = threadIdx.x;
  const size_t base = (size_t)blockIdx.x * 4096;
#pragma unroll 1
  for (int p = 0; p < 4; ++p) {
    const size_t L = base + (size_t)p * 1024 + (size_t)t * 4;
    if (L + 4 <= (size_t)NTOT) {
      float4 a = *reinterpret_cast<const float4*>(wr + L);
      float4 b = *reinterpret_cast<const float4*>(wi + L);
      float ae[4] = {a.x, a.y, a.z, a.w};
      float be[4] = {b.x, b.y, b.z, b.w};
#pragma unroll
      for (int e = 0; e < 4; ++e) {
        unsigned Li = (unsigned)L + e;
        unsigned co = Li / (unsigned)WMODE;      // c*64 + o
        unsigned m  = Li - co * (unsigned)WMODE;
        unsigned c = co >> 6, o = co & 63u;
        size_t D = ((((size_t)(o >> 1) * MG + (m >> 4)) * 64 + c) * 2 + (o & 1)) * 16 + (m & 15);
        Wpk[D] = (unsigned)f2bf(ae[e]) | ((unsigned)f2bf(be[e]) << 16);
      }
    } else {
#pragma unroll
      for (int e = 0; e < 4; ++e) {
        size_t Li = L + e;
        if (Li < (size_t)NTOT) {
          unsigned Lu = (unsigned)Li;
          unsigned co = Lu / (unsigned)WMODE;
          unsigned m  = Lu - co * (unsigned)WMODE;
          unsigned c = co >> 6, o = co & 63u;
          size_t D = ((((size_t)(o >> 1) * MG + (m >> 4)) * 64 + c) * 2 + (o & 1)) * 16 + (m & 15);
          Wpk[D] = (unsigned)f2bf(wr[Li]) | ((unsigned)f2bf(wi[Li]) << 16);
        }
      }
    }
  }
}

// --------------------------------------------------------------- forward DFT
__global__ __launch_bounds__(256) void spc_fwd_mfma(const float* __restrict__ x,
                                                    const s8v* __restrict__ T1,
                                                    const s8v* __restrict__ T2,
                                                    unsigned* __restrict__ X2u) {
  __shared__ short Wt[80 * 128];   // W1T[j][n] bf16, granule-4 XOR swizzle
  __shared__ float Gs[80 * 84];    // G f32, stride 84
  const int t = threadIdx.x;
  const int l = t & 63;
  const int w = t >> 6;
  const int lr = l & 15;
  const int lg = l >> 4;
  const int img = blockIdx.x;
  const float* xp = x + (size_t)img * (NH * NW);

  // stage 1: W1[n][j] = sum_m x[n][m] * Fw[j][m]; tiles (nt=2w..2w+1, jt 0..4)
  for (int nn = 0; nn < 2; ++nn) {
    const int nt = 2 * w + nn;
    const float* xrow = xp + (nt * 16 + lr) * NW + lg * 8;
    s8v a[4];
#pragma unroll
    for (int ks = 0; ks < 4; ++ks) {
      float4 f0 = *reinterpret_cast<const float4*>(xrow + ks * 32);
      float4 f1 = *reinterpret_cast<const float4*>(xrow + ks * 32 + 4);
      a[ks] = pack8(f0, f1);
    }
#pragma unroll
    for (int jt = 0; jt < 5; ++jt) {
      f4v acc = {0.f, 0.f, 0.f, 0.f};
#pragma unroll
      for (int ks = 0; ks < 4; ++ks) {
        s8v b = T1[(ks * 5 + jt) * 64 + l];
        acc = __builtin_amdgcn_mfma_f32_16x16x32_bf16(a[ks], b, acc, 0, 0, 0);
      }
      int j = jt * 16 + lr;
      int g = ((nt * 16 + lg * 4) >> 2) ^ ((j & 7) << 2);
      *reinterpret_cast<uint2*>(&Wt[j * 128 + g * 4]) = pack4(acc);
    }
  }
  __syncthreads();

  // stage 2: G[i][j] = sum_n Fh[i][n] * W1[n][j]; 25 tiles round-robin
  for (int tix = w; tix < 25; tix += 4) {
    int it = tix / 5, j2 = tix - 5 * it;
    int jrow = j2 * 16 + lr;
    f4v acc = {0.f, 0.f, 0.f, 0.f};
#pragma unroll
    for (int ks = 0; ks < 4; ++ks) {
      s8v afr = T2[(it * 4 + ks) * 64 + l];
      int g = (ks * 8 + lg * 2) ^ ((jrow & 7) << 2);
      s8v b = *reinterpret_cast<const s8v*>(&Wt[jrow * 128 + g * 4]);
      acc = __builtin_amdgcn_mfma_f32_16x16x32_bf16(afr, b, acc, 0, 0, 0);
    }
    int gi = it * 16 + lg * 4;
#pragma unroll
    for (int r = 0; r < 4; ++r) Gs[(gi + r) * 84 + jrow] = acc[r];
  }
  __syncthreads();

  // epilogue: X2r = G11 - G22, X2i = -(G12 + G21); packed bf16 pair per mode
  unsigned* X2p = X2u + (size_t)img * WMODE;
  for (int idx = t; idx < WMODE; idx += 256) {
    int i = idx / 33, j = idx - 33 * i;
    float g11 = Gs[i * 84 + j];
    float g22 = Gs[(i + 33) * 84 + (j + 33)];
    float g12 = Gs[i * 84 + (j + 33)];
    float g21 = Gs[(i + 33) * 84 + j];
    X2p[idx] = (unsigned)f2bf(g11 - g22) | ((unsigned)f2bf(-(g12 + g21)) << 16);
  }
}

// ------------------------------------------------------------------ X repack
// Xp[(m*64 + c)*16 + b] = X2u[(b*64 + c)*WMODE + m]; zero-filled for m in
// [WMODE, XPM). c chunk of 2 per block; grid (18, 32).
__global__ __launch_bounds__(256) void spc_xrepack(const unsigned* __restrict__ X2u,
                                                   unsigned* __restrict__ Xp) {
  __shared__ unsigned Ls[32 * 65];   // [row=cl*16+b][m_l], pad 65
  const int t = threadIdx.x;
  const int l = t & 63;
  const int w = t >> 6;
  const int m0 = blockIdx.x * 64;    // 18 chunks
  const int c0 = blockIdx.y * 2;     // 32 chunks

  {
    unsigned vv[8];
    const int m = m0 + l;
#pragma unroll
    for (int rr = 0; rr < 8; ++rr) {
      int r = w * 8 + rr;            // row = cl*16 + b
      int b = r & 15, cl = r >> 4;
      vv[rr] = (m < WMODE) ? X2u[(size_t)(b * 64 + c0 + cl) * WMODE + m] : 0u;
    }
#pragma unroll
    for (int rr = 0; rr < 8; ++rr)
      Ls[(w * 8 + rr) * 65 + l] = vv[rr];
  }
  __syncthreads();
  for (int p = 0; p < 8; ++p) {
    int m_l = p * 8 + w * 2 + (l >> 5);
    int m = m0 + m_l;
    if (m >= XPM) continue;
    int cl = (l >> 4) & 1, b = l & 15;
    unsigned v = Ls[(cl * 16 + b) * 65 + m_l];   // zero for m >= WMODE
    Xp[((size_t)m * 64 + c0 + cl) * 16 + b] = v;
  }
}

// ---------------------------------------------------------------- channel mix
// K[b,o,m] = sum_c X[b,c,m]*R[c,o,m]. Block = (opair, mg of 16 modes).
// Stage X slab (contiguous 64 KB of Xp) + W slab (contiguous 8 KB of Wpk)
// into LDS; inner c-loop is pure LDS + FMA. Outputs gathered in LDS, stored
// as coalesced uint2 runs into Kbf[img][ri][MPAD].
__global__ __launch_bounds__(512) void spc_vmix(const unsigned* __restrict__ Wpk,
                                                const unsigned* __restrict__ Xp,
                                                short* __restrict__ Kbf) {
  __shared__ unsigned Xl[16 * 1028];        // [m_l][c*16+b], row pad 4 (2-way banks)
  __shared__ unsigned Wl[2048];             // [c][oo][m_l]
  __shared__ unsigned short Ols[1024];      // [(oo*16+b)*2+ri][m_l]
  const int t = threadIdx.x;
  const int l = t & 63;
  const int w = t >> 6;
  const int opair = blockIdx.x;             // 32
  const int mg = blockIdx.y;                // 69
  const int m0 = mg * 16;

  // stage X: 4096 uint4, coalesced
  {
    const uint4* src = reinterpret_cast<const uint4*>(Xp + (size_t)m0 * 1024);
#pragma unroll
    for (int p = 0; p < 8; ++p) {
      int idx = p * 512 + t;                // 0..4095
      int row = idx >> 8, col = idx & 255;
      *reinterpret_cast<uint4*>(&Xl[row * 1028 + col * 4]) = src[idx];
    }
  }
  // stage W: 512 uint4, coalesced
  if (t < 512) {
    const uint4* src = reinterpret_cast<const uint4*>(
        Wpk + ((size_t)opair * MG + mg) * 2048);
    *reinterpret_cast<uint4*>(&Wl[t * 4]) = src[t];
  }
  __syncthreads();

  const int bg = w >> 1, oo = w & 1;
  const int m_l = l >> 2, bl = l & 3;
  const int xbase = m_l * 1028 + bg * 4 + bl;
  const int wbase = oo * 16 + m_l;

  float aR = 0.f, aI = 0.f;
#pragma unroll 4
  for (int c = 0; c < 64; ++c) {
    unsigned xv = Xl[xbase + c * 16];
    unsigned wv = Wl[wbase + c * 32];
    float xr = bflo(xv), xi = bfhi(xv);
    float wre = bflo(wv), wim = bfhi(wv);
    aR = fmaf(xr, wre, fmaf(-xi, wim, aR));
    aI = fmaf(xr, wim, fmaf( xi, wre, aI));
  }

  const int b = bg * 4 + bl;
  Ols[((oo * 16 + b) * 2 + 0) * 16 + m_l] = f2bf(aR);
  Ols[((oo * 16 + b) * 2 + 1) * 16 + m_l] = f2bf(aI);
  __syncthreads();

  if (t < 256) {
    const int pair = t >> 2, q = t & 3;     // pair = (oo*16+b)*2+ri
    if (!(mg == 68 && q > 0)) {             // edge group: only m 1088..1091
      const int oo2 = pair >> 5, b2 = (pair >> 1) & 15, ri = pair & 1;
      const size_t img = (size_t)b2 * 64 + opair * 2 + oo2;
      uint2 v = *reinterpret_cast<const uint2*>(&Ols[pair * 16 + q * 4]);
      *reinterpret_cast<uint2*>(Kbf + img * (2 * MPAD) + (size_t)ri * MPAD + m0 + q * 4) = v;
    }
  }
}

// ---------------------------------------------------------------- inverse DFT
__global__ __launch_bounds__(256) void spc_inv_mfma(const short* __restrict__ Kbf,
                                                    const s8v* __restrict__ T3,
                                                    const s8v* __restrict__ T4,
                                                    float* __restrict__ out) {
  __shared__ short Kls2[2 * MPAD];  // per-image K slice (4368 B)
  __shared__ short Vt[128 * 128];   // stacked [T1; -T2] rows i'<96, [m][i'] swizzled
  const int t = threadIdx.x;
  const int l = t & 63;
  const int w = t >> 6;
  const int lr = l & 15;
  const int lg = l >> 4;
  const int img = blockIdx.x;

  {
    const uint4* src = reinterpret_cast<const uint4*>(Kbf + (size_t)img * (2 * MPAD));
    uint4* dstl = reinterpret_cast<uint4*>(Kls2);
    for (int idx = t; idx < 273; idx += 256) dstl[idx] = src[idx];
  }
  __syncthreads();

  // build Kr/Ki A-fragments: [ri][it<3][ks<2], row i=it*16+lr, k j=ks*32+lg*8+e
  s8v fr[2][3][2];
#pragma unroll
  for (int ri2 = 0; ri2 < 2; ++ri2)
#pragma unroll
    for (int it = 0; it < 3; ++it)
#pragma unroll
      for (int ks = 0; ks < 2; ++ks) {
        const int i = it * 16 + lr;
#pragma unroll
        for (int e = 0; e < 8; ++e) {
          const int j = ks * 32 + lg * 8 + e;
          unsigned short v = (i < 33 && j < 33)
              ? (unsigned short)Kls2[ri2 * MPAD + i * 33 + j] : (unsigned short)0;
          fr[ri2][it][ks][e] = (short)v;
        }
      }

  // stage 1: T1[i][m] = Kr·Cw − Ki·Sw ; T2 = Ki·Cw + Kr·Sw ; store [T1; −T2]
  for (int mm = 0; mm < 2; ++mm) {
    const int mt = w * 2 + mm;
    const int m = mt * 16 + lr;
    s8v cw[2], sw[2], nsw[2];
#pragma unroll
    for (int ks = 0; ks < 2; ++ks) {
      cw[ks] = T3[((0 * 2 + ks) * 8 + mt) * 64 + l];
      sw[ks] = T3[((1 * 2 + ks) * 8 + mt) * 64 + l];
#pragma unroll
      for (int e = 0; e < 8; ++e)
        nsw[ks][e] = (short)(((unsigned short)sw[ks][e]) ^ 0x8000u);
    }
#pragma unroll
    for (int it = 0; it < 3; ++it) {
      f4v t1 = {0.f, 0.f, 0.f, 0.f}, t2 = {0.f, 0.f, 0.f, 0.f};
#pragma unroll
      for (int ks = 0; ks < 2; ++ks) {
        t1 = __builtin_amdgcn_mfma_f32_16x16x32_bf16(fr[0][it][ks], cw[ks],  t1, 0, 0, 0);
        t1 = __builtin_amdgcn_mfma_f32_16x16x32_bf16(fr[1][it][ks], nsw[ks], t1, 0, 0, 0);
        t2 = __builtin_amdgcn_mfma_f32_16x16x32_bf16(fr[1][it][ks], cw[ks],  t2, 0, 0, 0);
        t2 = __builtin_amdgcn_mfma_f32_16x16x32_bf16(fr[0][it][ks], sw[ks],  t2, 0, 0, 0);
      }
      const int base1 = it * 16 + lg * 4;
      const int g1 = (base1 >> 2) ^ ((m & 7) << 2);
      *reinterpret_cast<uint2*>(&Vt[m * 128 + g1 * 4]) = pack4(t1);
      f4v nt2v = {-t2[0], -t2[1], -t2[2], -t2[3]};
      const int g2 = ((48 + base1) >> 2) ^ ((m & 7) << 2);
      *reinterpret_cast<uint2*>(&Vt[m * 128 + g2 * 4]) = pack4(nt2v);
    }
  }
  __syncthreads();

  // stage 2: out[n][m] = sum_{i'<96} A2[n][i'] · Vt[i'][m]
  float* op = out + (size_t)img * (NH * NW);
  for (int nn = 0; nn < 2; ++nn) {
    const int nt = w * 2 + nn;
    s8v a[3];
#pragma unroll
    for (int ks = 0; ks < 3; ++ks) a[ks] = T4[(nt * 3 + ks) * 64 + l];
    for (int mt = 0; mt < 8; ++mt) {
      const int m = mt * 16 + lr;
      f4v acc = {0.f, 0.f, 0.f, 0.f};
#pragma unroll
      for (int ks = 0; ks < 3; ++ks) {
        const int g = (ks * 8 + lg * 2) ^ ((m & 7) << 2);
        s8v bb = *reinterpret_cast<const s8v*>(&Vt[m * 128 + g * 4]);
        acc = __builtin_amdgcn_mfma_f32_16x16x32_bf16(a[ks], bb, acc, 0, 0, 0);
      }
      const int n = nt * 16 + lg * 4;
#pragma unroll
      for (int r = 0; r < 4; ++r) op[(n + r) * NW + m] = acc[r];
    }
  }
}

// ---------------------------------------------------------------- launch
extern "C" void kernel_launch(void* const* d_in, const int* in_sizes, int n_in,
                              void* d_out, int out_size, void* d_ws, size_t ws_size,
                              hipStream_t stream) {
  const float* x  = (const float*)d_in[0];
  const float* wr = (const float*)d_in[1];
  const float* wi = (const float*)d_in[2];
  float* out = (float*)d_out;

  char* ws = (char*)d_ws;
  short* T1 = (short*)(ws);                    // 20480 B
  short* T2 = (short*)(ws + 20480);            // 20480 B
  short* T3 = (short*)(ws + 40960);            // 32768 B
  short* T4 = (short*)(ws + 73728);            // 24576 B  -> 98304
  unsigned* X2u = (unsigned*)(ws + 98304);     // 1024*1089*4 = 4,460,544 -> 4,558,848
  short* Kbf = (short*)(ws + 4558848);         // 1024*2184*2 = 4,472,832 -> 9,031,680
  unsigned* Xp = (unsigned*)(ws + 9031680);    // 1104*64*16*4 = 4,521,984 -> 13,553,664
  unsigned* Wpk = (unsigned*)(ws + 13553664);  // 32*69*2048*4 = 18,087,936 -> 31,641,600
  // total ~31.6 MB

  hipLaunchKernelGGL(spc_tables, dim3(192), dim3(256), 0, stream, T1, T2, T3, T4);
  hipLaunchKernelGGL(spc_wpack, dim3(1090), dim3(256), 0, stream, wr, wi, Wpk);
  hipLaunchKernelGGL(spc_fwd_mfma, dim3(NIMG), dim3(256), 0, stream,
                     x, (const s8v*)T1, (const s8v*)T2, X2u);
  hipLaunchKernelGGL(spc_xrepack, dim3(18, 32), dim3(256), 0, stream, X2u, Xp);
  hipLaunchKernelGGL(spc_vmix, dim3(32, MG), dim3(512), 0, stream,
                     Wpk, Xp, Kbf);
  hipLaunchKernelGGL(spc_inv_mfma, dim3(NIMG), dim3(256), 0, stream,
                     Kbf, (const s8v*)T3, (const s8v*)T4, out);
}

// Round 19
// 76.965 us; speedup vs baseline: 1.1708x; 1.1708x over previous
//
#include <hip/hip_runtime.h>

// SpectralConv2dRealFreq: B=16, Cin=Cout=64, H=W=128, modes=33 (k in [-16,16])
// out = Re( iDFT2_trunc( (DFT2_trunc(x)) * (wr + i*wi) ) ), separable 1/sqrt(N) DFTs.
//
// Round 19: halve the scattered-load lines.
//   wpack: PURELY LINEAR pack dst[i] = bf16(wr[i]) | bf16(wi[i])<<16 (no scatter
//          on either side; ~6 TB/s pattern). Weight bytes 36->18 MB.
//   vmix:  R11 structure; each scattered weight load now delivers BOTH wr & wi
//          (8 packed + 8 X loads per c4-batch, weight lines halved).
//   inv:   R11/R12 bf16-Kbf version. Weights bf16 (absmax 1.144409e-05, proven
//          identical to fp32-weight rounds in R5-R8/R17/R18).

#define NB   16
#define NC   64
#define NO   64
#define NH   128
#define NW   128
#define NM   33
#define WMODE (NM*NM)    // 1089 linear modes
#define MPAD  1092       // Kbf mode stride (16B-aligned pair stride)
#define NIMG 1024
#define NTOT (64*64*WMODE)   // 4,460,544 elements per weight plane

typedef __attribute__((ext_vector_type(8))) short s8v;   // 8 bf16 (4 VGPRs)
typedef __attribute__((ext_vector_type(4))) float f4v;   // MFMA accumulator

__device__ inline unsigned short f2bf(float f) {
  union { float f; unsigned u; } v; v.f = f;
  unsigned r = (v.u + 0x7FFFu + ((v.u >> 16) & 1u)) >> 16;   // RNE
  return (unsigned short)r;
}

__device__ inline float bflo(unsigned u) {
  union { unsigned u; float f; } cv; cv.u = u << 16; return cv.f;
}
__device__ inline float bfhi(unsigned u) {
  union { unsigned u; float f; } cv; cv.u = u & 0xFFFF0000u; return cv.f;
}

__device__ inline s8v pack8(float4 a, float4 b) {
  s8v r;
  r[0] = (short)f2bf(a.x); r[1] = (short)f2bf(a.y);
  r[2] = (short)f2bf(a.z); r[3] = (short)f2bf(a.w);
  r[4] = (short)f2bf(b.x); r[5] = (short)f2bf(b.y);
  r[6] = (short)f2bf(b.z); r[7] = (short)f2bf(b.w);
  return r;
}

__device__ inline uint2 pack4(f4v a) {
  uint2 p;
  p.x = (unsigned)f2bf(a[0]) | ((unsigned)f2bf(a[1]) << 16);
  p.y = (unsigned)f2bf(a[2]) | ((unsigned)f2bf(a[3]) << 16);
  return p;
}

// stacked-phase value: f in [0,33): cos row f; [33,66): sin row f-33; >=66: 0
__device__ inline unsigned short phase_bf(int f, int x) {
  if (f >= 66) return 0;
  int g = (f < 33) ? f : f - 33;
  int fr = (g <= 16) ? g : g + 95;          // signed freq mod 128
  int ph = (fr * x) & 127;                  // exact integer phase
  float ang = (float)ph * 0.04908738521234052f;   // 2*pi/128
  float v = ((f < 33) ? cosf(ang) : sinf(ang)) * 0.08838834764831845f;  // /sqrt(128)
  return f2bf(v);
}

// --------------------------------------------------- fragment-layout tables
__global__ __launch_bounds__(256) void spc_tables(short* __restrict__ T1,
                                                  short* __restrict__ T2,
                                                  short* __restrict__ T3,
                                                  short* __restrict__ T4) {
  int tid = blockIdx.x * 256 + threadIdx.x;
  if (tid >= 49152) return;
  int f, x; short* dst;
  if (tid < 10240) {
    int e = tid & 7, l = (tid >> 3) & 63, q = tid >> 9;     // q = ks*5+jt
    int ks = q / 5, jt = q - 5 * ks;
    f = jt * 16 + (l & 15); x = ks * 32 + (l >> 4) * 8 + e; dst = T1 + tid;
  } else if (tid < 20480) {
    int u = tid - 10240;
    int e = u & 7, l = (u >> 3) & 63, q = u >> 9;           // q = it*4+ks
    int it = q >> 2, ks = q & 3;
    f = it * 16 + (l & 15); x = ks * 32 + (l >> 4) * 8 + e; dst = T2 + u;
  } else if (tid < 36864) {
    int u = tid - 20480;
    int e = u & 7, l = (u >> 3) & 63, q = u >> 9;           // q = (cs*2+ks)*8+mt
    int cs = q >> 4, ks = (q >> 3) & 1, mt = q & 7;
    int j = ks * 32 + (l >> 4) * 8 + e;
    f = (j < 33) ? cs * 33 + j : 66;
    x = mt * 16 + (l & 15); dst = T3 + u;
  } else {
    int u = tid - 36864;
    int e = u & 7, l = (u >> 3) & 63, q = u >> 9;           // q = nt*3+ks
    int nt = q / 3, ks = q - 3 * nt;
    int i2 = ks * 32 + (l >> 4) * 8 + e;
    if (i2 < 48) f = (i2 < 33) ? i2 : 66;
    else         f = (i2 - 48 < 33) ? 33 + (i2 - 48) : 66;
    x = nt * 16 + (l & 15); dst = T4 + u;
  }
  *dst = (short)phase_bf(f, x);
}

// ------------------------------------------------------------ weight pack
// Purely linear: Wpk[i] = bf16(wr[i]) | bf16(wi[i])<<16.
// 1089 blocks x 256 threads x 4 float4-iters = 1,115,136 float4 = NTOT elems.
__global__ __launch_bounds__(256) void spc_wpack(const float* __restrict__ wr,
                                                 const float* __restrict__ wi,
                                                 unsigned* __restrict__ Wpk) {
  const size_t base = (size_t)blockIdx.x * 1024 + threadIdx.x;
#pragma unroll
  for (int p = 0; p < 4; ++p) {
    const size_t q = base + (size_t)p * 256;      // float4 index
    float4 a = *reinterpret_cast<const float4*>(wr + q * 4);
    float4 b = *reinterpret_cast<const float4*>(wi + q * 4);
    uint4 u;
    u.x = (unsigned)f2bf(a.x) | ((unsigned)f2bf(b.x) << 16);
    u.y = (unsigned)f2bf(a.y) | ((unsigned)f2bf(b.y) << 16);
    u.z = (unsigned)f2bf(a.z) | ((unsigned)f2bf(b.z) << 16);
    u.w = (unsigned)f2bf(a.w) | ((unsigned)f2bf(b.w) << 16);
    *reinterpret_cast<uint4*>(Wpk + q * 4) = u;
  }
}

// --------------------------------------------------------------- forward DFT
__global__ __launch_bounds__(256) void spc_fwd_mfma(const float* __restrict__ x,
                                                    const s8v* __restrict__ T1,
                                                    const s8v* __restrict__ T2,
                                                    unsigned* __restrict__ X2u) {
  __shared__ short Wt[80 * 128];   // W1T[j][n] bf16, granule-4 XOR swizzle
  __shared__ float Gs[80 * 84];    // G f32, stride 84
  const int t = threadIdx.x;
  const int l = t & 63;
  const int w = t >> 6;
  const int lr = l & 15;
  const int lg = l >> 4;
  const int img = blockIdx.x;
  const float* xp = x + (size_t)img * (NH * NW);

  // stage 1: W1[n][j] = sum_m x[n][m] * Fw[j][m]; tiles (nt=2w..2w+1, jt 0..4)
  for (int nn = 0; nn < 2; ++nn) {
    const int nt = 2 * w + nn;
    const float* xrow = xp + (nt * 16 + lr) * NW + lg * 8;
    s8v a[4];
#pragma unroll
    for (int ks = 0; ks < 4; ++ks) {
      float4 f0 = *reinterpret_cast<const float4*>(xrow + ks * 32);
      float4 f1 = *reinterpret_cast<const float4*>(xrow + ks * 32 + 4);
      a[ks] = pack8(f0, f1);
    }
#pragma unroll
    for (int jt = 0; jt < 5; ++jt) {
      f4v acc = {0.f, 0.f, 0.f, 0.f};
#pragma unroll
      for (int ks = 0; ks < 4; ++ks) {
        s8v b = T1[(ks * 5 + jt) * 64 + l];
        acc = __builtin_amdgcn_mfma_f32_16x16x32_bf16(a[ks], b, acc, 0, 0, 0);
      }
      int j = jt * 16 + lr;
      int g = ((nt * 16 + lg * 4) >> 2) ^ ((j & 7) << 2);
      *reinterpret_cast<uint2*>(&Wt[j * 128 + g * 4]) = pack4(acc);
    }
  }
  __syncthreads();

  // stage 2: G[i][j] = sum_n Fh[i][n] * W1[n][j]; 25 tiles round-robin
  for (int tix = w; tix < 25; tix += 4) {
    int it = tix / 5, j2 = tix - 5 * it;
    int jrow = j2 * 16 + lr;
    f4v acc = {0.f, 0.f, 0.f, 0.f};
#pragma unroll
    for (int ks = 0; ks < 4; ++ks) {
      s8v afr = T2[(it * 4 + ks) * 64 + l];
      int g = (ks * 8 + lg * 2) ^ ((jrow & 7) << 2);
      s8v b = *reinterpret_cast<const s8v*>(&Wt[jrow * 128 + g * 4]);
      acc = __builtin_amdgcn_mfma_f32_16x16x32_bf16(afr, b, acc, 0, 0, 0);
    }
    int gi = it * 16 + lg * 4;
#pragma unroll
    for (int r = 0; r < 4; ++r) Gs[(gi + r) * 84 + jrow] = acc[r];
  }
  __syncthreads();

  // epilogue: X2r = G11 - G22, X2i = -(G12 + G21); packed bf16 pair per mode
  unsigned* X2p = X2u + (size_t)img * WMODE;
  for (int idx = t; idx < WMODE; idx += 256) {
    int i = idx / 33, j = idx - 33 * i;
    float g11 = Gs[i * 84 + j];
    float g22 = Gs[(i + 33) * 84 + (j + 33)];
    float g12 = Gs[i * 84 + (j + 33)];
    float g21 = Gs[(i + 33) * 84 + j];
    X2p[idx] = (unsigned)f2bf(g11 - g22) | ((unsigned)f2bf(-(g12 + g21)) << 16);
  }
}

// ---------------------------------------------------------------- channel mix
// K[b,o,m] = sum_c X[b,c,m]*R[c,o,m] — elementwise along m for fixed (c,o).
// lane = m; wave = b-pair (8 waves); block = 2 o's x 64-mode chunk; grid 32x18.
// Weight loads are packed (wr|wi) uints: 8 loads/batch instead of 16.
__global__ __launch_bounds__(512) void spc_vmix(const unsigned* __restrict__ Wpk,
                                                const unsigned* __restrict__ X2u,
                                                short* __restrict__ Kbf) {
  const int t = threadIdx.x;
  const int ml = t & 63;
  const int w = t >> 6;              // wave 0..7 -> b pair {2w, 2w+1}
  const int b0 = w * 2;
  const int o0 = blockIdx.x * 2;     // 32 o-tiles
  const int m0 = blockIdx.y * 64;    // 18 m-chunks
  const int m = m0 + ml;
  const int mc = (m > 1088) ? 1088 : m;   // clamp for loads (edge chunk)

  const unsigned* wp = Wpk + (size_t)o0 * WMODE + mc;
  const unsigned* xp = X2u + (size_t)(b0 * 64) * WMODE + mc;
  const size_t cstepW = (size_t)64 * WMODE;   // c stride in weights

  float aR[2][2], aI[2][2];
#pragma unroll
  for (int j = 0; j < 2; ++j)
#pragma unroll
    for (int oo = 0; oo < 2; ++oo) { aR[j][oo] = 0.f; aI[j][oo] = 0.f; }

#pragma unroll 1   // bounded load window (round-10 lesson: full unroll -> spill)
  for (int c4 = 0; c4 < 16; ++c4) {
    // batch 16 independent loads (8 packed weight + 8 X) before any use
    unsigned wu[4][2];
    unsigned u[4][2];
#pragma unroll
    for (int q = 0; q < 4; ++q) {
      const int c = c4 * 4 + q;
#pragma unroll
      for (int oo = 0; oo < 2; ++oo)
        wu[q][oo] = wp[(size_t)c * cstepW + (size_t)oo * WMODE];
#pragma unroll
      for (int j = 0; j < 2; ++j)
        u[q][j] = xp[(size_t)(j * 64 + c) * WMODE];
    }
#pragma unroll
    for (int q = 0; q < 4; ++q) {
      float wrv[2], wiv[2];
#pragma unroll
      for (int oo = 0; oo < 2; ++oo) {
        wrv[oo] = bflo(wu[q][oo]);
        wiv[oo] = bfhi(wu[q][oo]);
      }
#pragma unroll
      for (int j = 0; j < 2; ++j) {
        const float xr_ = bflo(u[q][j]);
        const float xi_ = bfhi(u[q][j]);
#pragma unroll
        for (int oo = 0; oo < 2; ++oo) {
          aR[j][oo] = fmaf(xr_, wrv[oo], fmaf(-xi_, wiv[oo], aR[j][oo]));
          aI[j][oo] = fmaf(xr_, wiv[oo], fmaf( xi_, wrv[oo], aI[j][oo]));
        }
      }
    }
  }

  if (m < WMODE) {
#pragma unroll
    for (int j = 0; j < 2; ++j)
#pragma unroll
      for (int oo = 0; oo < 2; ++oo) {
        size_t img = (size_t)(b0 + j) * 64 + o0 + oo;
        Kbf[img * (2 * MPAD) + m]        = (short)f2bf(aR[j][oo]);
        Kbf[img * (2 * MPAD) + MPAD + m] = (short)f2bf(aI[j][oo]);
      }
  }
}

// ---------------------------------------------------------------- inverse DFT
__global__ __launch_bounds__(256) void spc_inv_mfma(const short* __restrict__ Kbf,
                                                    const s8v* __restrict__ T3,
                                                    const s8v* __restrict__ T4,
                                                    float* __restrict__ out) {
  __shared__ short Kls2[2 * MPAD];  // per-image K slice (4368 B)
  __shared__ short Vt[128 * 128];   // stacked [T1; -T2] rows i'<96, [m][i'] swizzled
  const int t = threadIdx.x;
  const int l = t & 63;
  const int w = t >> 6;
  const int lr = l & 15;
  const int lg = l >> 4;
  const int img = blockIdx.x;

  {
    const uint4* src = reinterpret_cast<const uint4*>(Kbf + (size_t)img * (2 * MPAD));
    uint4* dstl = reinterpret_cast<uint4*>(Kls2);
    for (int idx = t; idx < 273; idx += 256) dstl[idx] = src[idx];
  }
  __syncthreads();

  // build Kr/Ki A-fragments: [ri][it<3][ks<2], row i=it*16+lr, k j=ks*32+lg*8+e
  s8v fr[2][3][2];
#pragma unroll
  for (int ri2 = 0; ri2 < 2; ++ri2)
#pragma unroll
    for (int it = 0; it < 3; ++it)
#pragma unroll
      for (int ks = 0; ks < 2; ++ks) {
        const int i = it * 16 + lr;
#pragma unroll
        for (int e = 0; e < 8; ++e) {
          const int j = ks * 32 + lg * 8 + e;
          unsigned short v = (i < 33 && j < 33)
              ? (unsigned short)Kls2[ri2 * MPAD + i * 33 + j] : (unsigned short)0;
          fr[ri2][it][ks][e] = (short)v;
        }
      }

  // stage 1: T1[i][m] = Kr·Cw − Ki·Sw ; T2 = Ki·Cw + Kr·Sw ; store [T1; −T2]
  for (int mm = 0; mm < 2; ++mm) {
    const int mt = w * 2 + mm;
    const int m = mt * 16 + lr;
    s8v cw[2], sw[2], nsw[2];
#pragma unroll
    for (int ks = 0; ks < 2; ++ks) {
      cw[ks] = T3[((0 * 2 + ks) * 8 + mt) * 64 + l];
      sw[ks] = T3[((1 * 2 + ks) * 8 + mt) * 64 + l];
#pragma unroll
      for (int e = 0; e < 8; ++e)
        nsw[ks][e] = (short)(((unsigned short)sw[ks][e]) ^ 0x8000u);
    }
#pragma unroll
    for (int it = 0; it < 3; ++it) {
      f4v t1 = {0.f, 0.f, 0.f, 0.f}, t2 = {0.f, 0.f, 0.f, 0.f};
#pragma unroll
      for (int ks = 0; ks < 2; ++ks) {
        t1 = __builtin_amdgcn_mfma_f32_16x16x32_bf16(fr[0][it][ks], cw[ks],  t1, 0, 0, 0);
        t1 = __builtin_amdgcn_mfma_f32_16x16x32_bf16(fr[1][it][ks], nsw[ks], t1, 0, 0, 0);
        t2 = __builtin_amdgcn_mfma_f32_16x16x32_bf16(fr[1][it][ks], cw[ks],  t2, 0, 0, 0);
        t2 = __builtin_amdgcn_mfma_f32_16x16x32_bf16(fr[0][it][ks], sw[ks],  t2, 0, 0, 0);
      }
      const int base1 = it * 16 + lg * 4;
      const int g1 = (base1 >> 2) ^ ((m & 7) << 2);
      *reinterpret_cast<uint2*>(&Vt[m * 128 + g1 * 4]) = pack4(t1);
      f4v nt2v = {-t2[0], -t2[1], -t2[2], -t2[3]};
      const int g2 = ((48 + base1) >> 2) ^ ((m & 7) << 2);
      *reinterpret_cast<uint2*>(&Vt[m * 128 + g2 * 4]) = pack4(nt2v);
    }
  }
  __syncthreads();

  // stage 2: out[n][m] = sum_{i'<96} A2[n][i'] · Vt[i'][m]
  float* op = out + (size_t)img * (NH * NW);
  for (int nn = 0; nn < 2; ++nn) {
    const int nt = w * 2 + nn;
    s8v a[3];
#pragma unroll
    for (int ks = 0; ks < 3; ++ks) a[ks] = T4[(nt * 3 + ks) * 64 + l];
    for (int mt = 0; mt < 8; ++mt) {
      const int m = mt * 16 + lr;
      f4v acc = {0.f, 0.f, 0.f, 0.f};
#pragma unroll
      for (int ks = 0; ks < 3; ++ks) {
        const int g = (ks * 8 + lg * 2) ^ ((m & 7) << 2);
        s8v bb = *reinterpret_cast<const s8v*>(&Vt[m * 128 + g * 4]);
        acc = __builtin_amdgcn_mfma_f32_16x16x32_bf16(a[ks], bb, acc, 0, 0, 0);
      }
      const int n = nt * 16 + lg * 4;
#pragma unroll
      for (int r = 0; r < 4; ++r) op[(n + r) * NW + m] = acc[r];
    }
  }
}

// ---------------------------------------------------------------- launch
extern "C" void kernel_launch(void* const* d_in, const int* in_sizes, int n_in,
                              void* d_out, int out_size, void* d_ws, size_t ws_size,
                              hipStream_t stream) {
  const float* x  = (const float*)d_in[0];
  const float* wr = (const float*)d_in[1];
  const float* wi = (const float*)d_in[2];
  float* out = (float*)d_out;

  char* ws = (char*)d_ws;
  short* T1 = (short*)(ws);                    // 20480 B
  short* T2 = (short*)(ws + 20480);            // 20480 B
  short* T3 = (short*)(ws + 40960);            // 32768 B
  short* T4 = (short*)(ws + 73728);            // 24576 B  -> 98304
  unsigned* X2u = (unsigned*)(ws + 98304);     // 1024*1089*4 = 4,460,544 -> 4,558,848
  short* Kbf = (short*)(ws + 4558848);         // 1024*2184*2 = 4,472,832 -> 9,031,680
  unsigned* Wpk = (unsigned*)(ws + 9031680);   // 4,460,544*4 = 17,842,176 -> 26,873,856
  // total ~26.9 MB

  hipLaunchKernelGGL(spc_tables, dim3(192), dim3(256), 0, stream, T1, T2, T3, T4);
  hipLaunchKernelGGL(spc_wpack, dim3(1089), dim3(256), 0, stream, wr, wi, Wpk);
  hipLaunchKernelGGL(spc_fwd_mfma, dim3(NIMG), dim3(256), 0, stream,
                     x, (const s8v*)T1, (const s8v*)T2, X2u);
  hipLaunchKernelGGL(spc_vmix, dim3(32, 18), dim3(512), 0, stream,
                     Wpk, X2u, Kbf);
  hipLaunchKernelGGL(spc_inv_mfma, dim3(NIMG), dim3(256), 0, stream,
                     Kbf, (const s8v*)T3, (const s8v*)T4, out);
}